// Round 3
// baseline (189.222 us; speedup 1.0000x reference)
//
#include <hip/hip_runtime.h>
#include <hip/hip_bf16.h>
#include <stdint.h>

#define NB 2048
#define NR 10
#define ND 1024
#define NTGT (NB * (NR - 1))   /* 18432 targets */
#define NEMB (NB * NR)         /* 20480 embedding rows */
#define INV_TEMP 20.0f

#define BM 256
#define BN 256
#define BK 64
#define NKT (ND / BK)          /* 16 K-tiles */
#define TN_TILES (NTGT / BN)   /* 72 */

typedef __attribute__((ext_vector_type(8))) short short8;
typedef __attribute__((ext_vector_type(4))) float floatx4;

#define BAR()    asm volatile("s_barrier" ::: "memory")
#define LGKM0()  asm volatile("s_waitcnt lgkmcnt(0)" ::: "memory")
#define VMCNT0() asm volatile("s_waitcnt vmcnt(0)" ::: "memory")

__device__ __forceinline__ unsigned short f2bf(float f) {
  __hip_bfloat16 h = __float2bfloat16(f);
  return __builtin_bit_cast(unsigned short, h);
}

__device__ __forceinline__ void async16(const __hip_bfloat16* g, __hip_bfloat16* l) {
  __builtin_amdgcn_global_load_lds(
      (const __attribute__((address_space(1))) unsigned int*)g,
      (__attribute__((address_space(3))) unsigned int*)l,
      16, 0, 0);
}

// ---------------------------------------------------------------------------
// Kernel 1: L2-normalize all rows -> bf16 A (anchors) / T (targets) + inv_norms
// ---------------------------------------------------------------------------
__global__ __launch_bounds__(256) void normalize_kernel(
    const float* __restrict__ emb, __hip_bfloat16* __restrict__ Abf,
    __hip_bfloat16* __restrict__ Tbf, float* __restrict__ inv_norms) {
  int e = blockIdx.x * 4 + (threadIdx.x >> 6);
  int lane = threadIdx.x & 63;
  const float* row = emb + (size_t)e * ND;
  float4 v[4];
  float ss = 0.f;
#pragma unroll
  for (int p = 0; p < 4; ++p) {
    v[p] = reinterpret_cast<const float4*>(row)[lane + p * 64];
    ss += v[p].x * v[p].x + v[p].y * v[p].y + v[p].z * v[p].z + v[p].w * v[p].w;
  }
#pragma unroll
  for (int off = 32; off; off >>= 1) ss += __shfl_xor(ss, off, 64);
  float inv = 1.0f / fmaxf(sqrtf(ss), 1e-12f);
  if (lane == 0) inv_norms[e] = inv;

  int b = e / NR;
  int r = e - b * NR;
  __hip_bfloat16* dst;
  if (r == 0)      dst = Abf + (size_t)b * ND;
  else if (r == 1) dst = Tbf + (size_t)b * ND;
  else             dst = Tbf + (size_t)(NB + b * 8 + (r - 2)) * ND;

#pragma unroll
  for (int p = 0; p < 4; ++p) {
    ushort4 o;
    o.x = f2bf(v[p].x * inv);
    o.y = f2bf(v[p].y * inv);
    o.z = f2bf(v[p].z * inv);
    o.w = f2bf(v[p].w * inv);
    reinterpret_cast<ushort4*>(dst)[lane + p * 64] = o;
  }
}

// ---------------------------------------------------------------------------
// Kernel 2: exact fp32 row_scores -> KL per row + pos_score
// ---------------------------------------------------------------------------
__global__ __launch_bounds__(256) void rowkl_kernel(
    const float* __restrict__ emb, const float* __restrict__ scores,
    const float* __restrict__ inv_norms, float* __restrict__ pos_score,
    float* __restrict__ kl_out) {
  int b = blockIdx.x;
  int tid = threadIdx.x;
  int wid = tid >> 6, lane = tid & 63;
  const float* base = emb + (size_t)b * NR * ND;
  float4 av = reinterpret_cast<const float4*>(base)[tid];
  float part[9];
#pragma unroll
  for (int t = 0; t < 9; ++t) {
    float4 tv = reinterpret_cast<const float4*>(base + (size_t)(t + 1) * ND)[tid];
    part[t] = av.x * tv.x + av.y * tv.y + av.z * tv.z + av.w * tv.w;
  }
#pragma unroll
  for (int t = 0; t < 9; ++t) {
#pragma unroll
    for (int off = 32; off; off >>= 1) part[t] += __shfl_xor(part[t], off, 64);
  }
  __shared__ float red[4][9];
  if (lane == 0) {
#pragma unroll
    for (int t = 0; t < 9; ++t) red[wid][t] = part[t];
  }
  __syncthreads();
  if (tid == 0) {
    float inv_a = inv_norms[b * NR];
    float rs[9];
#pragma unroll
    for (int t = 0; t < 9; ++t)
      rs[t] = (red[0][t] + red[1][t] + red[2][t] + red[3][t]) * inv_a *
              inv_norms[b * NR + 1 + t];
    float sc[9], ms = -1e30f;
#pragma unroll
    for (int k = 0; k < 9; ++k) { sc[k] = scores[b * 9 + k]; ms = fmaxf(ms, sc[k]); }
    float se = 0.f;
#pragma unroll
    for (int k = 0; k < 9; ++k) { sc[k] = expf(sc[k] - ms); se += sc[k]; }
    float mr = -1e30f;
#pragma unroll
    for (int k = 0; k < 9; ++k) mr = fmaxf(mr, rs[k]);
    float sr = 0.f;
#pragma unroll
    for (int k = 0; k < 9; ++k) sr += expf(rs[k] - mr);
    float lz = logf(sr) + mr;
    float kl = 0.f;
#pragma unroll
    for (int k = 0; k < 9; ++k) {
      float ce = sc[k] / se;
      kl += ce * logf(ce) - ce * (rs[k] - lz);
    }
    kl_out[b] = kl / 9.0f;
    pos_score[b] = rs[0];
  }
}

// ---------------------------------------------------------------------------
// Kernel 3: 256x256x64 8-phase pipelined bf16 GEMM + sum-exp epilogue.
// Round-3 change: full next-K-tile staged at phase 0 (max slack ~3.5 phases),
// single vmcnt(0) drain after phase-3 MFMA. 7 barriers/iter.
// ---------------------------------------------------------------------------

__device__ __forceinline__ void stage_half(const __hip_bfloat16* __restrict__ gtile,
                                           __hip_bfloat16* lds, int rowoff, int k0,
                                           int tid) {
#pragma unroll
  for (int r = 0; r < 2; ++r) {
    int slot = r * 512 + tid;          // 0..1023
    int lrow = slot >> 3;              // 0..127
    int chunk = (slot & 7) ^ (lrow & 7);
    const __hip_bfloat16* src = gtile + (size_t)(rowoff + lrow) * ND + k0 + chunk * 8;
    __hip_bfloat16* dst = lds + rowoff * 64 + (r * 512 + (tid & ~63)) * 8;  // wave-uniform
    async16(src, dst);
  }
}

// Swizzled fragment read: logical (row, byte-in-row kb) -> short8
__device__ __forceinline__ short8 frag(const __hip_bfloat16* lds, int row, int kb) {
  int byte = row * 128 + (kb ^ ((row & 7) << 4));
  return *reinterpret_cast<const short8*>(reinterpret_cast<const char*>(lds) + byte);
}

__global__ __launch_bounds__(512, 2) void gemm_lse_kernel(
    const __hip_bfloat16* __restrict__ A, const __hip_bfloat16* __restrict__ T,
    float* __restrict__ sumexp) {
  __shared__ __hip_bfloat16 smem[2 * 2 * BM * BK];  // 128 KiB

  int bid = blockIdx.x;             // 576 = 8 * 72
  int tm = bid & 7;
  int tn = bid >> 3;

  int tid = threadIdx.x;
  int wid = tid >> 6, lane = tid & 63;
  int wm = wid >> 2, wn = wid & 3;  // 2 x 4 waves
  int lrow = lane & 15, lq = lane >> 4;

  const __hip_bfloat16* Ag = A + (size_t)tm * BM * ND;
  const __hip_bfloat16* Tg = T + (size_t)tn * BN * ND;

  floatx4 acc[8][4] = {};

  __hip_bfloat16* As0 = smem;
  __hip_bfloat16* Bs0 = smem + 16384;
  __hip_bfloat16* As1 = smem + 32768;
  __hip_bfloat16* Bs1 = smem + 49152;

  // Prologue: stage kt0 fully, drain once (cold), barrier.
  stage_half(Ag, As0, 0, 0, tid);
  stage_half(Ag, As0, 128, 0, tid);
  stage_half(Tg, Bs0, 0, 0, tid);
  stage_half(Tg, Bs0, 128, 0, tid);
  VMCNT0();
  BAR();

  for (int s = 0; s < NKT; ++s) {
    const int buf = s & 1;
    const __hip_bfloat16* Asb = buf ? As1 : As0;
    const __hip_bfloat16* Bsb = buf ? Bs1 : Bs0;
    __hip_bfloat16* Asn = buf ? As0 : As1;   // staging target for kt s+1
    __hip_bfloat16* Bsn = buf ? Bs0 : Bs1;
    const int k1 = (s + 1) * BK;
    const bool p1 = (s + 1) < NKT;

    short8 aF[4][2], b0[2][2], b1[2][2];

    // ---- phase 0: stage full kt s+1 (8 instr, max slack), read frags, MFMA Q(0,0)
    if (p1) {
      stage_half(Ag, Asn, 0, k1, tid);
      stage_half(Ag, Asn, 128, k1, tid);
      stage_half(Tg, Bsn, 0, k1, tid);
      stage_half(Tg, Bsn, 128, k1, tid);
    }
#pragma unroll
    for (int m = 0; m < 4; ++m)
#pragma unroll
      for (int kk = 0; kk < 2; ++kk)
        aF[m][kk] = frag(Asb, wm * 128 + m * 16 + lrow, kk * 64 + lq * 16);
#pragma unroll
    for (int n = 0; n < 2; ++n)
#pragma unroll
      for (int kk = 0; kk < 2; ++kk)
        b0[n][kk] = frag(Bsb, wn * 64 + n * 16 + lrow, kk * 64 + lq * 16);
    BAR();
    LGKM0();
    __builtin_amdgcn_s_setprio(1);
#pragma unroll
    for (int kk = 0; kk < 2; ++kk)
#pragma unroll
      for (int m = 0; m < 4; ++m)
#pragma unroll
        for (int n = 0; n < 2; ++n)
          acc[m][n] = __builtin_amdgcn_mfma_f32_16x16x32_bf16(aF[m][kk], b0[n][kk], acc[m][n], 0, 0, 0);
    __builtin_amdgcn_s_setprio(0);
    BAR();

    // ---- phase 1: read b1, MFMA Q(0,1)
#pragma unroll
    for (int n = 0; n < 2; ++n)
#pragma unroll
      for (int kk = 0; kk < 2; ++kk)
        b1[n][kk] = frag(Bsb, wn * 64 + (n + 2) * 16 + lrow, kk * 64 + lq * 16);
    BAR();
    LGKM0();
    __builtin_amdgcn_s_setprio(1);
#pragma unroll
    for (int kk = 0; kk < 2; ++kk)
#pragma unroll
      for (int m = 0; m < 4; ++m)
#pragma unroll
        for (int n = 0; n < 2; ++n)
          acc[m][n + 2] = __builtin_amdgcn_mfma_f32_16x16x32_bf16(aF[m][kk], b1[n][kk], acc[m][n + 2], 0, 0, 0);
    __builtin_amdgcn_s_setprio(0);
    BAR();

    // ---- phase 2: read aF(mh1), MFMA Q(1,0)
#pragma unroll
    for (int m = 0; m < 4; ++m)
#pragma unroll
      for (int kk = 0; kk < 2; ++kk)
        aF[m][kk] = frag(Asb, wm * 128 + (m + 4) * 16 + lrow, kk * 64 + lq * 16);
    BAR();
    LGKM0();
    __builtin_amdgcn_s_setprio(1);
#pragma unroll
    for (int kk = 0; kk < 2; ++kk)
#pragma unroll
      for (int m = 0; m < 4; ++m)
#pragma unroll
        for (int n = 0; n < 2; ++n)
          acc[m + 4][n] = __builtin_amdgcn_mfma_f32_16x16x32_bf16(aF[m][kk], b0[n][kk], acc[m + 4][n], 0, 0, 0);
    __builtin_amdgcn_s_setprio(0);
    BAR();

    // ---- phase 3: MFMA Q(1,1) (no new reads), then single drain + barrier
    __builtin_amdgcn_s_setprio(1);
#pragma unroll
    for (int kk = 0; kk < 2; ++kk)
#pragma unroll
      for (int m = 0; m < 4; ++m)
#pragma unroll
        for (int n = 0; n < 2; ++n)
          acc[m + 4][n + 2] = __builtin_amdgcn_mfma_f32_16x16x32_bf16(aF[m][kk], b1[n][kk], acc[m + 4][n + 2], 0, 0, 0);
    __builtin_amdgcn_s_setprio(0);
    __builtin_amdgcn_sched_barrier(0);   // pin: MFMA stays above the drain
    VMCNT0();                            // kt s+1 fully landed (issued ~3.5 phases ago)
    BAR();
  }

  // Epilogue: per C-row partial sum of exp(sim*20) over this block's 256 cols.
#pragma unroll
  for (int m = 0; m < 8; ++m) {
#pragma unroll
    for (int j = 0; j < 4; ++j) {
      float s = __expf(acc[m][0][j] * INV_TEMP) + __expf(acc[m][1][j] * INV_TEMP) +
                __expf(acc[m][2][j] * INV_TEMP) + __expf(acc[m][3][j] * INV_TEMP);
      s += __shfl_xor(s, 1, 64);
      s += __shfl_xor(s, 2, 64);
      s += __shfl_xor(s, 4, 64);
      s += __shfl_xor(s, 8, 64);
      if (lrow == 0) {
        int grow = tm * BM + wm * 128 + m * 16 + lq * 4 + j;
        atomicAdd(&sumexp[grow], s);
      }
    }
  }
}

// ---------------------------------------------------------------------------
// Kernel 4: final scalar reduction.
// ---------------------------------------------------------------------------
__global__ __launch_bounds__(256) void finalize_kernel(
    const float* __restrict__ sumexp, const float* __restrict__ pos_score,
    const float* __restrict__ kl, float* __restrict__ out) {
  int tid = threadIdx.x;
  float kls = 0.f, ces = 0.f;
  for (int i = tid; i < NB; i += 256) {
    kls += kl[i];
    ces += logf(sumexp[i]) - pos_score[i] * INV_TEMP;
  }
#pragma unroll
  for (int off = 32; off; off >>= 1) {
    kls += __shfl_xor(kls, off, 64);
    ces += __shfl_xor(ces, off, 64);
  }
  __shared__ float sk[4], se4[4];
  int wid = tid >> 6, lane = tid & 63;
  if (lane == 0) { sk[wid] = kls; se4[wid] = ces; }
  __syncthreads();
  if (tid == 0) {
    float k4 = sk[0] + sk[1] + sk[2] + sk[3];
    float e4 = se4[0] + se4[1] + se4[2] + se4[3];
    out[0] = 0.5f * (k4 / (float)NB) + 1.0f * (e4 / (float)NB);
  }
}

extern "C" void kernel_launch(void* const* d_in, const int* in_sizes, int n_in,
                              void* d_out, int out_size, void* d_ws, size_t ws_size,
                              hipStream_t stream) {
  const float* emb = (const float*)d_in[0];
  const float* scores = (const float*)d_in[1];
  float* out = (float*)d_out;

  char* ws = (char*)d_ws;
  size_t offA = 0;
  size_t offT = offA + (size_t)NB * ND * 2;
  size_t offInv = offT + (size_t)NTGT * ND * 2;
  size_t offSum = offInv + (size_t)NEMB * 4;
  size_t offPos = offSum + (size_t)NB * 4;
  size_t offKl = offPos + (size_t)NB * 4;

  __hip_bfloat16* Abf = (__hip_bfloat16*)(ws + offA);
  __hip_bfloat16* Tbf = (__hip_bfloat16*)(ws + offT);
  float* inv_norms = (float*)(ws + offInv);
  float* sumexp = (float*)(ws + offSum);
  float* pos_score = (float*)(ws + offPos);
  float* kl = (float*)(ws + offKl);

  hipMemsetAsync(sumexp, 0, (size_t)NB * 4, stream);
  normalize_kernel<<<NEMB / 4, 256, 0, stream>>>(emb, Abf, Tbf, inv_norms);
  rowkl_kernel<<<NB, 256, 0, stream>>>(emb, scores, inv_norms, pos_score, kl);
  gemm_lse_kernel<<<dim3(8 * TN_TILES), 512, 0, stream>>>(Abf, Tbf, sumexp);
  finalize_kernel<<<1, 256, 0, stream>>>(sumexp, pos_score, kl, out);
}

// Round 4
// 153.252 us; speedup vs baseline: 1.2347x; 1.2347x over previous
//
#include <hip/hip_runtime.h>
#include <hip/hip_bf16.h>
#include <stdint.h>

#define NB 2048
#define NR 10
#define ND 1024
#define NTGT (NB * (NR - 1))   /* 18432 targets */
#define NEMB (NB * NR)         /* 20480 embedding rows */
#define INV_TEMP 20.0f

#define BM 256
#define BN 256
#define BK 64
#define NKT (ND / BK)          /* 16 K-tiles */
#define TN_TILES (NTGT / BN)   /* 72 */

typedef __attribute__((ext_vector_type(8))) short short8;
typedef __attribute__((ext_vector_type(4))) float floatx4;

#define BAR()    asm volatile("s_barrier" ::: "memory")
#define LGKM0()  asm volatile("s_waitcnt lgkmcnt(0)" ::: "memory")
#define VMCNT0() asm volatile("s_waitcnt vmcnt(0)" ::: "memory")

__device__ __forceinline__ unsigned short f2bf(float f) {
  __hip_bfloat16 h = __float2bfloat16(f);
  return __builtin_bit_cast(unsigned short, h);
}

__device__ __forceinline__ void async16(const __hip_bfloat16* g, __hip_bfloat16* l) {
  __builtin_amdgcn_global_load_lds(
      (const __attribute__((address_space(1))) unsigned int*)g,
      (__attribute__((address_space(3))) unsigned int*)l,
      16, 0, 0);
}

// ---------------------------------------------------------------------------
// Kernel 1 (fused prep): one block per b. Reads the 10 rows of b ONCE:
// computes 10 norms + 9 anchor-dots, writes normalized bf16 A/T, KL, pos_score.
// Replaces the separate normalize + rowkl kernels (saves an 80 MB re-read).
// ---------------------------------------------------------------------------
__global__ __launch_bounds__(256) void prep_kernel(
    const float* __restrict__ emb, const float* __restrict__ scores,
    __hip_bfloat16* __restrict__ Abf, __hip_bfloat16* __restrict__ Tbf,
    float* __restrict__ pos_score, float* __restrict__ kl_out) {
  int b = blockIdx.x;
  int tid = threadIdx.x;             // float4 index within a row (256*4 = 1024)
  int wid = tid >> 6, lane = tid & 63;
  const float* base = emb + (size_t)b * NR * ND;

  float4 v[NR];
  float ss[NR], dt[NR - 1];
#pragma unroll
  for (int r = 0; r < NR; ++r) {
    v[r] = reinterpret_cast<const float4*>(base + (size_t)r * ND)[tid];
    ss[r] = v[r].x * v[r].x + v[r].y * v[r].y + v[r].z * v[r].z + v[r].w * v[r].w;
  }
#pragma unroll
  for (int t = 0; t < NR - 1; ++t)
    dt[t] = v[0].x * v[t + 1].x + v[0].y * v[t + 1].y + v[0].z * v[t + 1].z +
            v[0].w * v[t + 1].w;

#pragma unroll
  for (int off = 32; off; off >>= 1) {
#pragma unroll
    for (int r = 0; r < NR; ++r) ss[r] += __shfl_xor(ss[r], off, 64);
#pragma unroll
    for (int t = 0; t < NR - 1; ++t) dt[t] += __shfl_xor(dt[t], off, 64);
  }
  __shared__ float red[4][2 * NR - 1];
  if (lane == 0) {
#pragma unroll
    for (int r = 0; r < NR; ++r) red[wid][r] = ss[r];
#pragma unroll
    for (int t = 0; t < NR - 1; ++t) red[wid][NR + t] = dt[t];
  }
  __syncthreads();

  float inv[NR];
#pragma unroll
  for (int r = 0; r < NR; ++r) {
    float s = red[0][r] + red[1][r] + red[2][r] + red[3][r];
    inv[r] = 1.0f / fmaxf(sqrtf(s), 1e-12f);
  }

  // write normalized bf16 rows
#pragma unroll
  for (int r = 0; r < NR; ++r) {
    __hip_bfloat16* dst;
    if (r == 0)      dst = Abf + (size_t)b * ND;
    else if (r == 1) dst = Tbf + (size_t)b * ND;
    else             dst = Tbf + (size_t)(NB + b * 8 + (r - 2)) * ND;
    ushort4 o;
    o.x = f2bf(v[r].x * inv[r]);
    o.y = f2bf(v[r].y * inv[r]);
    o.z = f2bf(v[r].z * inv[r]);
    o.w = f2bf(v[r].w * inv[r]);
    reinterpret_cast<ushort4*>(dst)[tid] = o;
  }

  if (tid == 0) {
    float rs[NR - 1];
#pragma unroll
    for (int t = 0; t < NR - 1; ++t) {
      float d = red[0][NR + t] + red[1][NR + t] + red[2][NR + t] + red[3][NR + t];
      rs[t] = d * inv[0] * inv[t + 1];
    }
    float sc[NR - 1], ms = -1e30f;
#pragma unroll
    for (int k = 0; k < NR - 1; ++k) { sc[k] = scores[b * (NR - 1) + k]; ms = fmaxf(ms, sc[k]); }
    float se = 0.f;
#pragma unroll
    for (int k = 0; k < NR - 1; ++k) { sc[k] = expf(sc[k] - ms); se += sc[k]; }
    float mr = -1e30f;
#pragma unroll
    for (int k = 0; k < NR - 1; ++k) mr = fmaxf(mr, rs[k]);
    float sr = 0.f;
#pragma unroll
    for (int k = 0; k < NR - 1; ++k) sr += expf(rs[k] - mr);
    float lz = logf(sr) + mr;
    float kl = 0.f;
#pragma unroll
    for (int k = 0; k < NR - 1; ++k) {
      float ce = sc[k] / se;
      kl += ce * logf(ce) - ce * (rs[k] - lz);
    }
    kl_out[b] = kl / (float)(NR - 1);
    pos_score[b] = rs[0];
  }
}

// ---------------------------------------------------------------------------
// Kernel 2: 256x256x64 8-phase pipelined bf16 GEMM + sum-exp epilogue.
// Round-2 schedule (distributed staging, counted vmcnt(2)) + round-4 L2-local
// block mapping: co-resident blocks per XCD share 4 B-panels (L2-hot).
// ---------------------------------------------------------------------------

__device__ __forceinline__ void stage_half(const __hip_bfloat16* __restrict__ gtile,
                                           __hip_bfloat16* lds, int rowoff, int k0,
                                           int tid) {
#pragma unroll
  for (int r = 0; r < 2; ++r) {
    int slot = r * 512 + tid;          // 0..1023
    int lrow = slot >> 3;              // 0..127
    int chunk = (slot & 7) ^ (lrow & 7);
    const __hip_bfloat16* src = gtile + (size_t)(rowoff + lrow) * ND + k0 + chunk * 8;
    __hip_bfloat16* dst = lds + rowoff * 64 + (r * 512 + (tid & ~63)) * 8;  // wave-uniform
    async16(src, dst);
  }
}

// Swizzled fragment read: logical (row, byte-in-row kb) -> short8
__device__ __forceinline__ short8 frag(const __hip_bfloat16* lds, int row, int kb) {
  int byte = row * 128 + (kb ^ ((row & 7) << 4));
  return *reinterpret_cast<const short8*>(reinterpret_cast<const char*>(lds) + byte);
}

__global__ __launch_bounds__(512, 2) void gemm_lse_kernel(
    const __hip_bfloat16* __restrict__ A, const __hip_bfloat16* __restrict__ T,
    float* __restrict__ sumexp) {
  __shared__ __hip_bfloat16 smem[2 * 2 * BM * BK];  // 128 KiB

  int bid = blockIdx.x;             // 576 = 8 * 72
  // L2-locality mapping: xcd = bid&7 (round-robin dispatch); within an XCD,
  // 8 consecutive blocks share one B panel (tn), cycling tm 0..7.
  int xcd = bid & 7;
  int j = bid >> 3;                 // 0..71
  int tn = xcd * 9 + (j >> 3);      // 9 B-panels per XCD
  int tm = j & 7;

  int tid = threadIdx.x;
  int wid = tid >> 6, lane = tid & 63;
  int wm = wid >> 2, wn = wid & 3;  // 2 x 4 waves
  int lrow = lane & 15, lq = lane >> 4;

  const __hip_bfloat16* Ag = A + (size_t)tm * BM * ND;
  const __hip_bfloat16* Tg = T + (size_t)tn * BN * ND;

  floatx4 acc[8][4] = {};

  __hip_bfloat16* As0 = smem;
  __hip_bfloat16* Bs0 = smem + 16384;
  __hip_bfloat16* As1 = smem + 32768;
  __hip_bfloat16* Bs1 = smem + 49152;

  // Prologue: kt0 (4 half-tiles) + H0 of kt1; wait all but last half-tile.
  stage_half(Ag, As0, 0, 0, tid);
  stage_half(Ag, As0, 128, 0, tid);
  stage_half(Tg, Bs0, 0, 0, tid);
  stage_half(Tg, Bs0, 128, 0, tid);
  stage_half(Ag, As1, 0, BK, tid);
  asm volatile("s_waitcnt vmcnt(2)" ::: "memory");
  BAR();

  for (int s = 0; s < NKT; ++s) {
    const int buf = s & 1;
    const __hip_bfloat16* Asb = buf ? As1 : As0;
    const __hip_bfloat16* Bsb = buf ? Bs1 : Bs0;
    __hip_bfloat16* Asn = buf ? As0 : As1;   // staging target for kt s+1
    __hip_bfloat16* Bsn = buf ? Bs0 : Bs1;
    __hip_bfloat16* Asf = buf ? As1 : As0;   // staging target for kt s+2 (same parity)
    const int k1 = (s + 1) * BK, k2 = (s + 2) * BK;
    const bool p1 = (s + 1) < NKT, p2 = (s + 2) < NKT;

    short8 aF[4][2], b0[2][2], b1[2][2];

    // ---- phase 0: Q(mh0,nh0) ----
#pragma unroll
    for (int m = 0; m < 4; ++m)
#pragma unroll
      for (int kk = 0; kk < 2; ++kk)
        aF[m][kk] = frag(Asb, wm * 128 + m * 16 + lrow, kk * 64 + lq * 16);
#pragma unroll
    for (int n = 0; n < 2; ++n)
#pragma unroll
      for (int kk = 0; kk < 2; ++kk)
        b0[n][kk] = frag(Bsb, wn * 64 + n * 16 + lrow, kk * 64 + lq * 16);
    if (p1) stage_half(Ag, Asn, 128, k1, tid);           // H1(s+1)
    BAR();
    LGKM0();
    __builtin_amdgcn_s_setprio(1);
#pragma unroll
    for (int kk = 0; kk < 2; ++kk)
#pragma unroll
      for (int m = 0; m < 4; ++m)
#pragma unroll
        for (int n = 0; n < 2; ++n)
          acc[m][n] = __builtin_amdgcn_mfma_f32_16x16x32_bf16(aF[m][kk], b0[n][kk], acc[m][n], 0, 0, 0);
    __builtin_amdgcn_s_setprio(0);
    BAR();

    // ---- phase 1: Q(mh0,nh1) ----
#pragma unroll
    for (int n = 0; n < 2; ++n)
#pragma unroll
      for (int kk = 0; kk < 2; ++kk)
        b1[n][kk] = frag(Bsb, wn * 64 + (n + 2) * 16 + lrow, kk * 64 + lq * 16);
    if (p1) stage_half(Tg, Bsn, 0, k1, tid);             // H2(s+1)
    BAR();
    LGKM0();
    __builtin_amdgcn_s_setprio(1);
#pragma unroll
    for (int kk = 0; kk < 2; ++kk)
#pragma unroll
      for (int m = 0; m < 4; ++m)
#pragma unroll
        for (int n = 0; n < 2; ++n)
          acc[m][n + 2] = __builtin_amdgcn_mfma_f32_16x16x32_bf16(aF[m][kk], b1[n][kk], acc[m][n + 2], 0, 0, 0);
    __builtin_amdgcn_s_setprio(0);
    BAR();

    // ---- phase 2: Q(mh1,nh0) ----
#pragma unroll
    for (int m = 0; m < 4; ++m)
#pragma unroll
      for (int kk = 0; kk < 2; ++kk)
        aF[m][kk] = frag(Asb, wm * 128 + (m + 4) * 16 + lrow, kk * 64 + lq * 16);
    if (p1) stage_half(Tg, Bsn, 128, k1, tid);           // H3(s+1)
    BAR();
    LGKM0();
    __builtin_amdgcn_s_setprio(1);
#pragma unroll
    for (int kk = 0; kk < 2; ++kk)
#pragma unroll
      for (int m = 0; m < 4; ++m)
#pragma unroll
        for (int n = 0; n < 2; ++n)
          acc[m + 4][n] = __builtin_amdgcn_mfma_f32_16x16x32_bf16(aF[m][kk], b0[n][kk], acc[m + 4][n], 0, 0, 0);
    __builtin_amdgcn_s_setprio(0);
    BAR();

    // ---- phase 3: Q(mh1,nh1) ----
    if (p2) {
      stage_half(Ag, Asf, 0, k2, tid);                   // H0(s+2)
      asm volatile("s_waitcnt vmcnt(2)" ::: "memory");   // kt s+1 fully landed
    } else {
      asm volatile("s_waitcnt vmcnt(0)" ::: "memory");
    }
    BAR();
    __builtin_amdgcn_s_setprio(1);
#pragma unroll
    for (int kk = 0; kk < 2; ++kk)
#pragma unroll
      for (int m = 0; m < 4; ++m)
#pragma unroll
        for (int n = 0; n < 2; ++n)
          acc[m + 4][n + 2] = __builtin_amdgcn_mfma_f32_16x16x32_bf16(aF[m][kk], b1[n][kk], acc[m + 4][n + 2], 0, 0, 0);
    __builtin_amdgcn_s_setprio(0);
    BAR();
  }

  // Epilogue: per C-row partial sum of exp(sim*20) over this block's 256 cols.
#pragma unroll
  for (int m = 0; m < 8; ++m) {
#pragma unroll
    for (int j2 = 0; j2 < 4; ++j2) {
      float s = __expf(acc[m][0][j2] * INV_TEMP) + __expf(acc[m][1][j2] * INV_TEMP) +
                __expf(acc[m][2][j2] * INV_TEMP) + __expf(acc[m][3][j2] * INV_TEMP);
      s += __shfl_xor(s, 1, 64);
      s += __shfl_xor(s, 2, 64);
      s += __shfl_xor(s, 4, 64);
      s += __shfl_xor(s, 8, 64);
      if (lrow == 0) {
        int grow = tm * BM + wm * 128 + m * 16 + lq * 4 + j2;
        atomicAdd(&sumexp[grow], s);
      }
    }
  }
}

// ---------------------------------------------------------------------------
// Kernel 3: final scalar reduction.
// ---------------------------------------------------------------------------
__global__ __launch_bounds__(256) void finalize_kernel(
    const float* __restrict__ sumexp, const float* __restrict__ pos_score,
    const float* __restrict__ kl, float* __restrict__ out) {
  int tid = threadIdx.x;
  float kls = 0.f, ces = 0.f;
  for (int i = tid; i < NB; i += 256) {
    kls += kl[i];
    ces += logf(sumexp[i]) - pos_score[i] * INV_TEMP;
  }
#pragma unroll
  for (int off = 32; off; off >>= 1) {
    kls += __shfl_xor(kls, off, 64);
    ces += __shfl_xor(ces, off, 64);
  }
  __shared__ float sk[4], se4[4];
  int wid = tid >> 6, lane = tid & 63;
  if (lane == 0) { sk[wid] = kls; se4[wid] = ces; }
  __syncthreads();
  if (tid == 0) {
    float k4 = sk[0] + sk[1] + sk[2] + sk[3];
    float e4 = se4[0] + se4[1] + se4[2] + se4[3];
    out[0] = 0.5f * (k4 / (float)NB) + 1.0f * (e4 / (float)NB);
  }
}

extern "C" void kernel_launch(void* const* d_in, const int* in_sizes, int n_in,
                              void* d_out, int out_size, void* d_ws, size_t ws_size,
                              hipStream_t stream) {
  const float* emb = (const float*)d_in[0];
  const float* scores = (const float*)d_in[1];
  float* out = (float*)d_out;

  char* ws = (char*)d_ws;
  size_t offA = 0;
  size_t offT = offA + (size_t)NB * ND * 2;
  size_t offSum = offT + (size_t)NTGT * ND * 2;
  size_t offPos = offSum + (size_t)NB * 4;
  size_t offKl = offPos + (size_t)NB * 4;

  __hip_bfloat16* Abf = (__hip_bfloat16*)(ws + offA);
  __hip_bfloat16* Tbf = (__hip_bfloat16*)(ws + offT);
  float* sumexp = (float*)(ws + offSum);
  float* pos_score = (float*)(ws + offPos);
  float* kl = (float*)(ws + offKl);

  hipMemsetAsync(sumexp, 0, (size_t)NB * 4, stream);
  prep_kernel<<<NB, 256, 0, stream>>>(emb, scores, Abf, Tbf, pos_score, kl);
  gemm_lse_kernel<<<dim3(8 * TN_TILES), 512, 0, stream>>>(Abf, Tbf, sumexp);
  finalize_kernel<<<1, 256, 0, stream>>>(sumexp, pos_score, kl, out);
}

// Round 5
// 151.425 us; speedup vs baseline: 1.2496x; 1.0121x over previous
//
#include <hip/hip_runtime.h>
#include <hip/hip_bf16.h>
#include <stdint.h>

#define NB 2048
#define NR 10
#define ND 1024
#define NTGT (NB * (NR - 1))   /* 18432 targets */
#define NEMB (NB * NR)         /* 20480 embedding rows */
#define INV_TEMP 20.0f

#define BM 256
#define BN 192
#define BK 64
#define NKT (ND / BK)          /* 16 K-tiles */
#define TN_TILES (NTGT / BN)   /* 96 */

typedef __attribute__((ext_vector_type(8))) short short8;
typedef __attribute__((ext_vector_type(4))) float floatx4;

#define BAR()    asm volatile("s_barrier" ::: "memory")
#define LGKM0()  asm volatile("s_waitcnt lgkmcnt(0)" ::: "memory")
#define VMCNT0() asm volatile("s_waitcnt vmcnt(0)" ::: "memory")

__device__ __forceinline__ unsigned short f2bf(float f) {
  __hip_bfloat16 h = __float2bfloat16(f);
  return __builtin_bit_cast(unsigned short, h);
}

__device__ __forceinline__ void async16(const __hip_bfloat16* g, __hip_bfloat16* l) {
  __builtin_amdgcn_global_load_lds(
      (const __attribute__((address_space(1))) unsigned int*)g,
      (__attribute__((address_space(3))) unsigned int*)l,
      16, 0, 0);
}

// ---------------------------------------------------------------------------
// Kernel 1 (fused prep): one block per b. Reads the 10 rows of b ONCE:
// computes 10 norms + 9 anchor-dots, writes normalized bf16 A/T, KL, pos_score.
// ---------------------------------------------------------------------------
__global__ __launch_bounds__(256) void prep_kernel(
    const float* __restrict__ emb, const float* __restrict__ scores,
    __hip_bfloat16* __restrict__ Abf, __hip_bfloat16* __restrict__ Tbf,
    float* __restrict__ pos_score, float* __restrict__ kl_out) {
  int b = blockIdx.x;
  int tid = threadIdx.x;             // float4 index within a row (256*4 = 1024)
  int wid = tid >> 6, lane = tid & 63;
  const float* base = emb + (size_t)b * NR * ND;

  float4 v[NR];
  float ss[NR], dt[NR - 1];
#pragma unroll
  for (int r = 0; r < NR; ++r) {
    v[r] = reinterpret_cast<const float4*>(base + (size_t)r * ND)[tid];
    ss[r] = v[r].x * v[r].x + v[r].y * v[r].y + v[r].z * v[r].z + v[r].w * v[r].w;
  }
#pragma unroll
  for (int t = 0; t < NR - 1; ++t)
    dt[t] = v[0].x * v[t + 1].x + v[0].y * v[t + 1].y + v[0].z * v[t + 1].z +
            v[0].w * v[t + 1].w;

#pragma unroll
  for (int off = 32; off; off >>= 1) {
#pragma unroll
    for (int r = 0; r < NR; ++r) ss[r] += __shfl_xor(ss[r], off, 64);
#pragma unroll
    for (int t = 0; t < NR - 1; ++t) dt[t] += __shfl_xor(dt[t], off, 64);
  }
  __shared__ float red[4][2 * NR - 1];
  if (lane == 0) {
#pragma unroll
    for (int r = 0; r < NR; ++r) red[wid][r] = ss[r];
#pragma unroll
    for (int t = 0; t < NR - 1; ++t) red[wid][NR + t] = dt[t];
  }
  __syncthreads();

  float inv[NR];
#pragma unroll
  for (int r = 0; r < NR; ++r) {
    float s = red[0][r] + red[1][r] + red[2][r] + red[3][r];
    inv[r] = 1.0f / fmaxf(sqrtf(s), 1e-12f);
  }

#pragma unroll
  for (int r = 0; r < NR; ++r) {
    __hip_bfloat16* dst;
    if (r == 0)      dst = Abf + (size_t)b * ND;
    else if (r == 1) dst = Tbf + (size_t)b * ND;
    else             dst = Tbf + (size_t)(NB + b * 8 + (r - 2)) * ND;
    ushort4 o;
    o.x = f2bf(v[r].x * inv[r]);
    o.y = f2bf(v[r].y * inv[r]);
    o.z = f2bf(v[r].z * inv[r]);
    o.w = f2bf(v[r].w * inv[r]);
    reinterpret_cast<ushort4*>(dst)[tid] = o;
  }

  if (tid == 0) {
    float rs[NR - 1];
#pragma unroll
    for (int t = 0; t < NR - 1; ++t) {
      float d = red[0][NR + t] + red[1][NR + t] + red[2][NR + t] + red[3][NR + t];
      rs[t] = d * inv[0] * inv[t + 1];
    }
    float sc[NR - 1], ms = -1e30f;
#pragma unroll
    for (int k = 0; k < NR - 1; ++k) { sc[k] = scores[b * (NR - 1) + k]; ms = fmaxf(ms, sc[k]); }
    float se = 0.f;
#pragma unroll
    for (int k = 0; k < NR - 1; ++k) { sc[k] = expf(sc[k] - ms); se += sc[k]; }
    float mr = -1e30f;
#pragma unroll
    for (int k = 0; k < NR - 1; ++k) mr = fmaxf(mr, rs[k]);
    float sr = 0.f;
#pragma unroll
    for (int k = 0; k < NR - 1; ++k) sr += expf(rs[k] - mr);
    float lz = logf(sr) + mr;
    float kl = 0.f;
#pragma unroll
    for (int k = 0; k < NR - 1; ++k) {
      float ce = sc[k] / se;
      kl += ce * logf(ce) - ce * (rs[k] - lz);
    }
    kl_out[b] = kl / (float)(NR - 1);
    pos_score[b] = rs[0];
  }
}

// ---------------------------------------------------------------------------
// Kernel 2: 256x192x64 8-phase pipelined bf16 GEMM + sum-exp epilogue.
// Grid = 768 blocks = exactly 3 full rounds of 256 CUs (zero tail waste).
// ---------------------------------------------------------------------------

// Stage a 128-row x 64-col chunk (2 loads/thread).
__device__ __forceinline__ void stage_half(const __hip_bfloat16* __restrict__ gtile,
                                           __hip_bfloat16* lds, int rowoff, int k0,
                                           int tid) {
#pragma unroll
  for (int r = 0; r < 2; ++r) {
    int slot = r * 512 + tid;          // 0..1023
    int lrow = slot >> 3;              // 0..127
    int chunk = (slot & 7) ^ (lrow & 7);
    const __hip_bfloat16* src = gtile + (size_t)(rowoff + lrow) * ND + k0 + chunk * 8;
    __hip_bfloat16* dst = lds + rowoff * 64 + (r * 512 + (tid & ~63)) * 8;  // wave-uniform
    async16(src, dst);
  }
}

// Stage a 64-row x 64-col chunk (1 load/thread).
__device__ __forceinline__ void stage_quarter(const __hip_bfloat16* __restrict__ gtile,
                                              __hip_bfloat16* lds, int rowoff, int k0,
                                              int tid) {
  int lrow = tid >> 3;                 // 0..63
  int chunk = (tid & 7) ^ (lrow & 7);
  const __hip_bfloat16* src = gtile + (size_t)(rowoff + lrow) * ND + k0 + chunk * 8;
  __hip_bfloat16* dst = lds + rowoff * 64 + (tid & ~63) * 8;  // wave-uniform
  async16(src, dst);
}

// Swizzled fragment read: logical (row, byte-in-row kb) -> short8
__device__ __forceinline__ short8 frag(const __hip_bfloat16* lds, int row, int kb) {
  int byte = row * 128 + (kb ^ ((row & 7) << 4));
  return *reinterpret_cast<const short8*>(reinterpret_cast<const char*>(lds) + byte);
}

__global__ __launch_bounds__(512, 2) void gemm_lse_kernel(
    const __hip_bfloat16* __restrict__ A, const __hip_bfloat16* __restrict__ T,
    float* __restrict__ sumexp) {
  // 112 KiB: [As0 256x64][Bs0 192x64][As1 256x64][Bs1 192x64]
  __shared__ __hip_bfloat16 smem[2 * (BM + BN) * BK];

  int bid = blockIdx.x;             // 768 = 8 * 96
  int xcd = bid & 7;
  int j = bid >> 3;                 // 0..95
  int tn = xcd * 12 + (j >> 3);     // 12 B-panels per XCD
  int tm = j & 7;

  int tid = threadIdx.x;
  int wid = tid >> 6, lane = tid & 63;
  int wm = wid >> 2, wn = wid & 3;  // 2 x 4 waves; wave tile 128 x 48
  int lrow = lane & 15, lq = lane >> 4;

  const __hip_bfloat16* Ag = A + (size_t)tm * BM * ND;
  const __hip_bfloat16* Tg = T + (size_t)tn * BN * ND;

  floatx4 acc[8][3] = {};

  __hip_bfloat16* As0 = smem;
  __hip_bfloat16* Bs0 = smem + BM * BK;                     // +16384
  __hip_bfloat16* As1 = smem + BM * BK + BN * BK;           // +28672
  __hip_bfloat16* Bs1 = smem + 2 * BM * BK + BN * BK;       // +45056

  // Prologue: kt0 fully (7 loads/thread) + A0(kt1) (2); wait the 7.
  stage_half(Ag, As0, 0, 0, tid);
  stage_half(Ag, As0, 128, 0, tid);
  stage_quarter(Tg, Bs0, 0, 0, tid);
  stage_quarter(Tg, Bs0, 64, 0, tid);
  stage_quarter(Tg, Bs0, 128, 0, tid);
  stage_half(Ag, As1, 0, BK, tid);
  asm volatile("s_waitcnt vmcnt(2)" ::: "memory");
  BAR();

  for (int s = 0; s < NKT; ++s) {
    const int buf = s & 1;
    const __hip_bfloat16* Asb = buf ? As1 : As0;
    const __hip_bfloat16* Bsb = buf ? Bs1 : Bs0;
    __hip_bfloat16* Asn = buf ? As0 : As1;   // staging target for kt s+1
    __hip_bfloat16* Bsn = buf ? Bs0 : Bs1;
    __hip_bfloat16* Asf = buf ? As1 : As0;   // staging target for kt s+2 (same parity)
    const int k1 = (s + 1) * BK, k2 = (s + 2) * BK;
    const bool p1 = (s + 1) < NKT, p2 = (s + 2) < NKT;

    short8 aF[4][2], bA[2], bB[2][2];

    // ---- phase 0: read aF(mh0) + b(n0); stage A1(s+1); MFMA acc[0..3][0]
#pragma unroll
    for (int m = 0; m < 4; ++m)
#pragma unroll
      for (int kk = 0; kk < 2; ++kk)
        aF[m][kk] = frag(Asb, wm * 128 + m * 16 + lrow, kk * 64 + lq * 16);
#pragma unroll
    for (int kk = 0; kk < 2; ++kk)
      bA[kk] = frag(Bsb, wn * 48 + lrow, kk * 64 + lq * 16);
    if (p1) stage_half(Ag, Asn, 128, k1, tid);
    BAR();
    LGKM0();
    __builtin_amdgcn_s_setprio(1);
#pragma unroll
    for (int kk = 0; kk < 2; ++kk)
#pragma unroll
      for (int m = 0; m < 4; ++m)
        acc[m][0] = __builtin_amdgcn_mfma_f32_16x16x32_bf16(aF[m][kk], bA[kk], acc[m][0], 0, 0, 0);
    __builtin_amdgcn_s_setprio(0);
    BAR();

    // ---- phase 1: read b(n1,n2); stage B0,B1(s+1); MFMA acc[0..3][1,2]
#pragma unroll
    for (int n = 0; n < 2; ++n)
#pragma unroll
      for (int kk = 0; kk < 2; ++kk)
        bB[n][kk] = frag(Bsb, wn * 48 + (n + 1) * 16 + lrow, kk * 64 + lq * 16);
    if (p1) {
      stage_quarter(Tg, Bsn, 0, k1, tid);
      stage_quarter(Tg, Bsn, 64, k1, tid);
    }
    BAR();
    LGKM0();
    __builtin_amdgcn_s_setprio(1);
#pragma unroll
    for (int kk = 0; kk < 2; ++kk)
#pragma unroll
      for (int m = 0; m < 4; ++m)
#pragma unroll
        for (int n = 0; n < 2; ++n)
          acc[m][n + 1] = __builtin_amdgcn_mfma_f32_16x16x32_bf16(aF[m][kk], bB[n][kk], acc[m][n + 1], 0, 0, 0);
    __builtin_amdgcn_s_setprio(0);
    BAR();

    // ---- phase 2: read aF(mh1); stage B2(s+1); MFMA acc[4..7][0]
#pragma unroll
    for (int m = 0; m < 4; ++m)
#pragma unroll
      for (int kk = 0; kk < 2; ++kk)
        aF[m][kk] = frag(Asb, wm * 128 + (m + 4) * 16 + lrow, kk * 64 + lq * 16);
    if (p1) stage_quarter(Tg, Bsn, 128, k1, tid);
    BAR();
    LGKM0();
    __builtin_amdgcn_s_setprio(1);
#pragma unroll
    for (int kk = 0; kk < 2; ++kk)
#pragma unroll
      for (int m = 0; m < 4; ++m)
        acc[m + 4][0] = __builtin_amdgcn_mfma_f32_16x16x32_bf16(aF[m][kk], bA[kk], acc[m + 4][0], 0, 0, 0);
    __builtin_amdgcn_s_setprio(0);
    BAR();

    // ---- phase 3: stage A0(s+2) + counted vmcnt; MFMA acc[4..7][1,2]
    if (p2) {
      stage_half(Ag, Asf, 0, k2, tid);
      asm volatile("s_waitcnt vmcnt(2)" ::: "memory");   // kt s+1 fully landed
    } else {
      asm volatile("s_waitcnt vmcnt(0)" ::: "memory");
    }
    BAR();
    __builtin_amdgcn_s_setprio(1);
#pragma unroll
    for (int kk = 0; kk < 2; ++kk)
#pragma unroll
      for (int m = 0; m < 4; ++m)
#pragma unroll
        for (int n = 0; n < 2; ++n)
          acc[m + 4][n + 1] = __builtin_amdgcn_mfma_f32_16x16x32_bf16(aF[m][kk], bB[n][kk], acc[m + 4][n + 1], 0, 0, 0);
    __builtin_amdgcn_s_setprio(0);
    BAR();
  }

  // Epilogue: per C-row partial sum of exp(sim*20) over this block's 192 cols.
#pragma unroll
  for (int m = 0; m < 8; ++m) {
#pragma unroll
    for (int j2 = 0; j2 < 4; ++j2) {
      float s = __expf(acc[m][0][j2] * INV_TEMP) + __expf(acc[m][1][j2] * INV_TEMP) +
                __expf(acc[m][2][j2] * INV_TEMP);
      s += __shfl_xor(s, 1, 64);
      s += __shfl_xor(s, 2, 64);
      s += __shfl_xor(s, 4, 64);
      s += __shfl_xor(s, 8, 64);
      if (lrow == 0) {
        int grow = tm * BM + wm * 128 + m * 16 + lq * 4 + j2;
        atomicAdd(&sumexp[grow], s);
      }
    }
  }
}

// ---------------------------------------------------------------------------
// Kernel 3: final scalar reduction.
// ---------------------------------------------------------------------------
__global__ __launch_bounds__(256) void finalize_kernel(
    const float* __restrict__ sumexp, const float* __restrict__ pos_score,
    const float* __restrict__ kl, float* __restrict__ out) {
  int tid = threadIdx.x;
  float kls = 0.f, ces = 0.f;
  for (int i = tid; i < NB; i += 256) {
    kls += kl[i];
    ces += logf(sumexp[i]) - pos_score[i] * INV_TEMP;
  }
#pragma unroll
  for (int off = 32; off; off >>= 1) {
    kls += __shfl_xor(kls, off, 64);
    ces += __shfl_xor(ces, off, 64);
  }
  __shared__ float sk[4], se4[4];
  int wid = tid >> 6, lane = tid & 63;
  if (lane == 0) { sk[wid] = kls; se4[wid] = ces; }
  __syncthreads();
  if (tid == 0) {
    float k4 = sk[0] + sk[1] + sk[2] + sk[3];
    float e4 = se4[0] + se4[1] + se4[2] + se4[3];
    out[0] = 0.5f * (k4 / (float)NB) + 1.0f * (e4 / (float)NB);
  }
}

extern "C" void kernel_launch(void* const* d_in, const int* in_sizes, int n_in,
                              void* d_out, int out_size, void* d_ws, size_t ws_size,
                              hipStream_t stream) {
  const float* emb = (const float*)d_in[0];
  const float* scores = (const float*)d_in[1];
  float* out = (float*)d_out;

  char* ws = (char*)d_ws;
  size_t offA = 0;
  size_t offT = offA + (size_t)NB * ND * 2;
  size_t offSum = offT + (size_t)NTGT * ND * 2;
  size_t offPos = offSum + (size_t)NB * 4;
  size_t offKl = offPos + (size_t)NB * 4;

  __hip_bfloat16* Abf = (__hip_bfloat16*)(ws + offA);
  __hip_bfloat16* Tbf = (__hip_bfloat16*)(ws + offT);
  float* sumexp = (float*)(ws + offSum);
  float* pos_score = (float*)(ws + offPos);
  float* kl = (float*)(ws + offKl);

  hipMemsetAsync(sumexp, 0, (size_t)NB * 4, stream);
  prep_kernel<<<NB, 256, 0, stream>>>(emb, scores, Abf, Tbf, pos_score, kl);
  gemm_lse_kernel<<<dim3(8 * TN_TILES), 512, 0, stream>>>(Abf, Tbf, sumexp);
  finalize_kernel<<<1, 256, 0, stream>>>(sumexp, pos_score, kl, out);
}

// Round 6
// 141.269 us; speedup vs baseline: 1.3394x; 1.0719x over previous
//
#include <hip/hip_runtime.h>
#include <hip/hip_bf16.h>
#include <stdint.h>

#define NB 2048
#define NR 10
#define ND 1024
#define NTGT (NB * (NR - 1))   /* 18432 targets */
#define NEMB (NB * NR)         /* 20480 embedding rows */
#define INV_TEMP 20.0f

#define BM 128
#define BN 256
#define BK 32
#define NKT (ND / BK)          /* 32 K-tiles */
#define TM_TILES (NB / BM)     /* 16 */
#define TN_TILES (NTGT / BN)   /* 72 */

typedef __attribute__((ext_vector_type(8))) short short8;
typedef __attribute__((ext_vector_type(4))) float floatx4;

#define BAR()    asm volatile("s_barrier" ::: "memory")
#define LGKM0()  asm volatile("s_waitcnt lgkmcnt(0)" ::: "memory")
#define VMCNT0() asm volatile("s_waitcnt vmcnt(0)" ::: "memory")

__device__ __forceinline__ unsigned short f2bf(float f) {
  __hip_bfloat16 h = __float2bfloat16(f);
  return __builtin_bit_cast(unsigned short, h);
}

__device__ __forceinline__ void async16(const __hip_bfloat16* g, __hip_bfloat16* l) {
  __builtin_amdgcn_global_load_lds(
      (const __attribute__((address_space(1))) unsigned int*)g,
      (__attribute__((address_space(3))) unsigned int*)l,
      16, 0, 0);
}

// ---------------------------------------------------------------------------
// Kernel 1 (fused prep): one block per b. Reads the 10 rows of b ONCE:
// computes 10 norms + 9 anchor-dots, writes normalized bf16 A/T, KL, pos_score.
// ---------------------------------------------------------------------------
__global__ __launch_bounds__(256) void prep_kernel(
    const float* __restrict__ emb, const float* __restrict__ scores,
    __hip_bfloat16* __restrict__ Abf, __hip_bfloat16* __restrict__ Tbf,
    float* __restrict__ pos_score, float* __restrict__ kl_out) {
  int b = blockIdx.x;
  int tid = threadIdx.x;             // float4 index within a row (256*4 = 1024)
  int wid = tid >> 6, lane = tid & 63;
  const float* base = emb + (size_t)b * NR * ND;

  float4 v[NR];
  float ss[NR], dt[NR - 1];
#pragma unroll
  for (int r = 0; r < NR; ++r) {
    v[r] = reinterpret_cast<const float4*>(base + (size_t)r * ND)[tid];
    ss[r] = v[r].x * v[r].x + v[r].y * v[r].y + v[r].z * v[r].z + v[r].w * v[r].w;
  }
#pragma unroll
  for (int t = 0; t < NR - 1; ++t)
    dt[t] = v[0].x * v[t + 1].x + v[0].y * v[t + 1].y + v[0].z * v[t + 1].z +
            v[0].w * v[t + 1].w;

#pragma unroll
  for (int off = 32; off; off >>= 1) {
#pragma unroll
    for (int r = 0; r < NR; ++r) ss[r] += __shfl_xor(ss[r], off, 64);
#pragma unroll
    for (int t = 0; t < NR - 1; ++t) dt[t] += __shfl_xor(dt[t], off, 64);
  }
  __shared__ float red[4][2 * NR - 1];
  if (lane == 0) {
#pragma unroll
    for (int r = 0; r < NR; ++r) red[wid][r] = ss[r];
#pragma unroll
    for (int t = 0; t < NR - 1; ++t) red[wid][NR + t] = dt[t];
  }
  __syncthreads();

  float inv[NR];
#pragma unroll
  for (int r = 0; r < NR; ++r) {
    float s = red[0][r] + red[1][r] + red[2][r] + red[3][r];
    inv[r] = 1.0f / fmaxf(sqrtf(s), 1e-12f);
  }

#pragma unroll
  for (int r = 0; r < NR; ++r) {
    __hip_bfloat16* dst;
    if (r == 0)      dst = Abf + (size_t)b * ND;
    else if (r == 1) dst = Tbf + (size_t)b * ND;
    else             dst = Tbf + (size_t)(NB + b * 8 + (r - 2)) * ND;
    ushort4 o;
    o.x = f2bf(v[r].x * inv[r]);
    o.y = f2bf(v[r].y * inv[r]);
    o.z = f2bf(v[r].z * inv[r]);
    o.w = f2bf(v[r].w * inv[r]);
    reinterpret_cast<ushort4*>(dst)[tid] = o;
  }

  if (tid == 0) {
    float rs[NR - 1];
#pragma unroll
    for (int t = 0; t < NR - 1; ++t) {
      float d = red[0][NR + t] + red[1][NR + t] + red[2][NR + t] + red[3][NR + t];
      rs[t] = d * inv[0] * inv[t + 1];
    }
    float sc[NR - 1], ms = -1e30f;
#pragma unroll
    for (int k = 0; k < NR - 1; ++k) { sc[k] = scores[b * (NR - 1) + k]; ms = fmaxf(ms, sc[k]); }
    float se = 0.f;
#pragma unroll
    for (int k = 0; k < NR - 1; ++k) { sc[k] = expf(sc[k] - ms); se += sc[k]; }
    float mr = -1e30f;
#pragma unroll
    for (int k = 0; k < NR - 1; ++k) mr = fmaxf(mr, rs[k]);
    float sr = 0.f;
#pragma unroll
    for (int k = 0; k < NR - 1; ++k) sr += expf(rs[k] - mr);
    float lz = logf(sr) + mr;
    float kl = 0.f;
#pragma unroll
    for (int k = 0; k < NR - 1; ++k) {
      float ce = sc[k] / se;
      kl += ce * logf(ce) - ce * (rs[k] - lz);
    }
    kl_out[b] = kl / (float)(NR - 1);
    pos_score[b] = rs[0];
  }
}

// ---------------------------------------------------------------------------
// Kernel 2: 128x256x32 dbuf bf16 GEMM + sum-exp epilogue, 2 blocks/CU (TLP).
// 48 KiB LDS, VGPR forced <=128 via __launch_bounds__(512,4).
// Rows are 64 B in LDS; swizzle: 16B-chunk ^= (row & 3).
// ---------------------------------------------------------------------------

// Stage A-tile K-slice: 128 rows x 32 cols, 1 load/thread.
__device__ __forceinline__ void stage_A(const __hip_bfloat16* __restrict__ gtile,
                                        __hip_bfloat16* lds, int k0, int tid) {
  int lrow = tid >> 2;                 // 0..127
  int chunk = (tid & 3) ^ (lrow & 3);
  const __hip_bfloat16* src = gtile + (size_t)lrow * ND + k0 + chunk * 8;
  __hip_bfloat16* dst = lds + (tid & ~63) * 8;  // wave-uniform base, lane*16B auto
  async16(src, dst);
}

// Stage B-tile K-slice: 256 rows x 32 cols, 2 loads/thread.
__device__ __forceinline__ void stage_B(const __hip_bfloat16* __restrict__ gtile,
                                        __hip_bfloat16* lds, int k0, int tid) {
#pragma unroll
  for (int r = 0; r < 2; ++r) {
    int slot = r * 512 + tid;          // 0..1023
    int lrow = slot >> 2;              // 0..255
    int chunk = (slot & 3) ^ (lrow & 3);
    const __hip_bfloat16* src = gtile + (size_t)lrow * ND + k0 + chunk * 8;
    __hip_bfloat16* dst = lds + (r * 512 + (tid & ~63)) * 8;
    async16(src, dst);
  }
}

// Swizzled fragment read: logical (row, lq) -> short8. Row stride 64 B.
__device__ __forceinline__ short8 frag(const __hip_bfloat16* lds, int row, int lq) {
  int byte = row * 64 + ((lq * 16) ^ ((row & 3) << 4));
  return *reinterpret_cast<const short8*>(reinterpret_cast<const char*>(lds) + byte);
}

__global__ __launch_bounds__(512, 4) void gemm_lse_kernel(
    const __hip_bfloat16* __restrict__ A, const __hip_bfloat16* __restrict__ T,
    float* __restrict__ sumexp) {
  // 48 KiB: [As0 128x32][Bs0 256x32][As1][Bs1]
  __shared__ __hip_bfloat16 smem[2 * (BM + BN) * BK];

  int bid = blockIdx.x;             // 1152 = 8 * 144
  int xcd = bid & 7;
  int j = bid >> 3;                 // 0..143
  int tn = xcd * 9 + (j >> 4);      // 9 B-panels per XCD
  int tm = j & 15;

  int tid = threadIdx.x;
  int wid = tid >> 6, lane = tid & 63;
  int wm = wid >> 2, wn = wid & 3;  // 2 x 4 waves; wave tile 64 x 64
  int lrow = lane & 15, lq = lane >> 4;

  const __hip_bfloat16* Ag = A + (size_t)tm * BM * ND;
  const __hip_bfloat16* Tg = T + (size_t)tn * BN * ND;

  floatx4 acc[4][4] = {};

  __hip_bfloat16* As0 = smem;                          // 4096 elems
  __hip_bfloat16* Bs0 = smem + BM * BK;                // 8192 elems
  __hip_bfloat16* As1 = smem + (BM + BN) * BK;
  __hip_bfloat16* Bs1 = smem + (2 * BM + BN) * BK;

  // Prologue: stage kt0 (3 loads/thread), drain (cold), barrier.
  stage_A(Ag, As0, 0, tid);
  stage_B(Tg, Bs0, 0, tid);
  VMCNT0();
  BAR();

#pragma unroll 2
  for (int s = 0; s < NKT; ++s) {
    const int buf = s & 1;
    const __hip_bfloat16* Asb = buf ? As1 : As0;
    const __hip_bfloat16* Bsb = buf ? Bs1 : Bs0;
    __hip_bfloat16* Asn = buf ? As0 : As1;   // staging target for kt s+1
    __hip_bfloat16* Bsn = buf ? Bs0 : Bs1;
    const int kn = ((s + 1) & (NKT - 1)) * BK;  // wrap: last iter re-stages kt0
                                                // into the dead buffer (harmless)

    short8 aF[4], bF[2];

    // ---- phase 0: stage full kt s+1 (3 loads); read aF + b(n0,n1); MFMA n0,n1
    stage_A(Ag, Asn, kn, tid);
    stage_B(Tg, Bsn, kn, tid);
#pragma unroll
    for (int m = 0; m < 4; ++m)
      aF[m] = frag(Asb, wm * 64 + m * 16 + lrow, lq);
#pragma unroll
    for (int n = 0; n < 2; ++n)
      bF[n] = frag(Bsb, wn * 64 + n * 16 + lrow, lq);
    BAR();
    LGKM0();
    __builtin_amdgcn_s_setprio(1);
#pragma unroll
    for (int m = 0; m < 4; ++m)
#pragma unroll
      for (int n = 0; n < 2; ++n)
        acc[m][n] = __builtin_amdgcn_mfma_f32_16x16x32_bf16(aF[m], bF[n], acc[m][n], 0, 0, 0);
    __builtin_amdgcn_s_setprio(0);
    BAR();

    // ---- phase 1: read b(n2,n3); MFMA n2,n3; drain pinned after MFMA
#pragma unroll
    for (int n = 0; n < 2; ++n)
      bF[n] = frag(Bsb, wn * 64 + (n + 2) * 16 + lrow, lq);
    BAR();
    LGKM0();
    __builtin_amdgcn_s_setprio(1);
#pragma unroll
    for (int m = 0; m < 4; ++m)
#pragma unroll
      for (int n = 0; n < 2; ++n)
        acc[m][n + 2] = __builtin_amdgcn_mfma_f32_16x16x32_bf16(aF[m], bF[n], acc[m][n + 2], 0, 0, 0);
    __builtin_amdgcn_s_setprio(0);
    __builtin_amdgcn_sched_barrier(0);   // keep MFMA above the drain
    VMCNT0();                            // kt s+1 landed (issued ~1.5 phases ago;
                                         // cross-block TLP covers the residual)
    BAR();
  }

  VMCNT0();  // drain the wrapped final-iteration stages before LDS goes away

  // Epilogue: per C-row partial sum of exp(sim*20) over this block's 256 cols.
#pragma unroll
  for (int m = 0; m < 4; ++m) {
#pragma unroll
    for (int j2 = 0; j2 < 4; ++j2) {
      float s = __expf(acc[m][0][j2] * INV_TEMP) + __expf(acc[m][1][j2] * INV_TEMP) +
                __expf(acc[m][2][j2] * INV_TEMP) + __expf(acc[m][3][j2] * INV_TEMP);
      s += __shfl_xor(s, 1, 64);
      s += __shfl_xor(s, 2, 64);
      s += __shfl_xor(s, 4, 64);
      s += __shfl_xor(s, 8, 64);
      if (lrow == 0) {
        int grow = tm * BM + wm * 64 + m * 16 + lq * 4 + j2;
        atomicAdd(&sumexp[grow], s);
      }
    }
  }
}

// ---------------------------------------------------------------------------
// Kernel 3: final scalar reduction.
// ---------------------------------------------------------------------------
__global__ __launch_bounds__(256) void finalize_kernel(
    const float* __restrict__ sumexp, const float* __restrict__ pos_score,
    const float* __restrict__ kl, float* __restrict__ out) {
  int tid = threadIdx.x;
  float kls = 0.f, ces = 0.f;
  for (int i = tid; i < NB; i += 256) {
    kls += kl[i];
    ces += logf(sumexp[i]) - pos_score[i] * INV_TEMP;
  }
#pragma unroll
  for (int off = 32; off; off >>= 1) {
    kls += __shfl_xor(kls, off, 64);
    ces += __shfl_xor(ces, off, 64);
  }
  __shared__ float sk[4], se4[4];
  int wid = tid >> 6, lane = tid & 63;
  if (lane == 0) { sk[wid] = kls; se4[wid] = ces; }
  __syncthreads();
  if (tid == 0) {
    float k4 = sk[0] + sk[1] + sk[2] + sk[3];
    float e4 = se4[0] + se4[1] + se4[2] + se4[3];
    out[0] = 0.5f * (k4 / (float)NB) + 1.0f * (e4 / (float)NB);
  }
}

extern "C" void kernel_launch(void* const* d_in, const int* in_sizes, int n_in,
                              void* d_out, int out_size, void* d_ws, size_t ws_size,
                              hipStream_t stream) {
  const float* emb = (const float*)d_in[0];
  const float* scores = (const float*)d_in[1];
  float* out = (float*)d_out;

  char* ws = (char*)d_ws;
  size_t offA = 0;
  size_t offT = offA + (size_t)NB * ND * 2;
  size_t offSum = offT + (size_t)NTGT * ND * 2;
  size_t offPos = offSum + (size_t)NB * 4;
  size_t offKl = offPos + (size_t)NB * 4;

  __hip_bfloat16* Abf = (__hip_bfloat16*)(ws + offA);
  __hip_bfloat16* Tbf = (__hip_bfloat16*)(ws + offT);
  float* sumexp = (float*)(ws + offSum);
  float* pos_score = (float*)(ws + offPos);
  float* kl = (float*)(ws + offKl);

  hipMemsetAsync(sumexp, 0, (size_t)NB * 4, stream);
  prep_kernel<<<NB, 256, 0, stream>>>(emb, scores, Abf, Tbf, pos_score, kl);
  gemm_lse_kernel<<<dim3(8 * TM_TILES * TN_TILES / 8), 512, 0, stream>>>(Abf, Tbf, sumexp);
  finalize_kernel<<<1, 256, 0, stream>>>(sumexp, pos_score, kl, out);
}